// Round 6
// baseline (46111.362 us; speedup 1.0000x reference)
//
#include <hip/hip_runtime.h>
#include <hip/hip_cooperative_groups.h>

#define B_ 64
#define H_ 1024
#define IN_ 512
#define S_ 256
#define L_ 6
#define NG_ 4096
#define NWGF 768             // 6 layers * 128 col-slices (8 H-cols x 4 gates)
#define NTICK (S_ + L_ - 1)

typedef __bf16 bf16x8 __attribute__((ext_vector_type(8)));
typedef float f32x4 __attribute__((ext_vector_type(4)));
typedef float f32x2 __attribute__((ext_vector_type(2)));
typedef unsigned short ushort4v __attribute__((ext_vector_type(4)));
typedef unsigned short ushort_t;

#define OFF_U0 0ul
#define OFF_V0 2097152ul
#define OFF_UL(l) (6291456ul + (unsigned long)((l) - 1) * 8388608ul)
#define OFF_VL(l) (OFF_UL(l) + 4194304ul)
#define WT_BYTES 96468992ul
#define XB_BYTES 16777216ul
#define HRING_BYTES 3145728ul   // 4 slots * L*B*H * 2B
#define FLAGS_BYTES 6144ul      // L * S * 4B

#define MFMA16(a, b, c) __builtin_amdgcn_mfma_f32_16x16x32_bf16(a, b, c, 0, 0, 0)
#define BAR() __builtin_amdgcn_s_barrier()
#define WAITV6() asm volatile("s_waitcnt vmcnt(6)" ::: "memory")
#define WAITV3() asm volatile("s_waitcnt vmcnt(3)" ::: "memory")
#define WAITV0() asm volatile("s_waitcnt vmcnt(0)" ::: "memory")

__device__ __forceinline__ unsigned short f2bf(float f) {
  union { float f; unsigned u; } v; v.f = f;
  unsigned r = v.u + 0x7fffu + ((v.u >> 16) & 1u);
  return (unsigned short)(r >> 16);
}

__device__ __forceinline__ void gload_lds(const ushort_t* g, ushort_t* l) {
  __builtin_amdgcn_global_load_lds(
      (const __attribute__((address_space(1))) unsigned int*)g,
      (__attribute__((address_space(3))) unsigned int*)l, 16, 0, 0);
}

__device__ __forceinline__ void waitflag(const int* p) {
  if (threadIdx.x == 0) {
    while (__hip_atomic_load(p, __ATOMIC_ACQUIRE, __HIP_MEMORY_SCOPE_AGENT) < 128)
      __builtin_amdgcn_s_sleep(8);
    __threadfence();
  }
  __syncthreads();
}

// ---- one-time weight transpose + bf16 convert: Wt[n][k] = bf16(W[k][n]) ----
__global__ void k_transpose_bf16(const float* __restrict__ W,
                                 unsigned short* __restrict__ Wt,
                                 int K, int N) {
  __shared__ float tile[32][33];
  int n0 = blockIdx.x * 32, k0 = blockIdx.y * 32;
  int tx = threadIdx.x, ty = threadIdx.y; // 32 x 8
#pragma unroll
  for (int i = 0; i < 32; i += 8)
    tile[ty + i][tx] = W[(size_t)(k0 + ty + i) * N + (n0 + tx)];
  __syncthreads();
#pragma unroll
  for (int i = 0; i < 32; i += 8)
    Wt[(size_t)(n0 + ty + i) * K + (k0 + tx)] = f2bf(tile[tx][ty + i]);
}

// ---- one-time x -> bf16, layout [S][B][IN] ----
__global__ void k_cvt_x(const float* __restrict__ x, ushort_t* __restrict__ xb) {
  int t = blockIdx.x, b = blockIdx.y, k = threadIdx.x * 4;
  float4 v = *(const float4*)(x + ((size_t)b * S_ + t) * IN_ + k);
  ushort4v o = { f2bf(v.x), f2bf(v.y), f2bf(v.z), f2bf(v.w) };
  *(ushort4v*)(xb + ((size_t)t * B_ + b) * IN_ + k) = o;
}

// ============== flag-synchronized dataflow LSTM (no grid.sync) ==============
__global__ void __launch_bounds__(256, 3)
k_lstm_flag(const ushort_t* __restrict__ xb,
            const ushort_t* __restrict__ Wt,
            const float* __restrict__ b0,
            const float* __restrict__ bL,
            ushort_t* __restrict__ hring,  // [4][L][B][H] bf16, pre-zeroed
            int* __restrict__ flags,       // [L][S], pre-zeroed
            float* __restrict__ out) {
  float* __restrict__ seq = out;                           // [B][S][H]
  float* __restrict__ hf = out + (size_t)B_ * S_ * H_;     // [L][B][H]
  float* __restrict__ cf = hf + (size_t)L_ * B_ * H_;      // [L][B][H]

  // 4-deep chunk ring: each chunk = 4KB W (32 rows x 64K) + 8KB A (64 x 64K).
  // zs (gate staging, 10KB) aliases ring[0] after the pipeline drains.
  __shared__ __align__(16) ushort_t ring[4][6144];
  float* zsb = (float*)&ring[0][0];

  const int tid = threadIdx.x;
  const int w = tid >> 6;        // wave: A-rows w*16..w*16+15; stages gate w of W
  const int lane = tid & 63;
  const int l15 = lane & 15;
  const int kg = lane >> 4;
  const int wg = blockIdx.x;

  const int l = wg >> 7;
  const int jb = wg & 127;
  const int hcol0 = jb << 3;
  const int KU = (l == 0) ? IN_ : H_;
  const int nU = KU >> 6;
  const int nch = nU + (H_ >> 6);        // 24 or 32 (both %4 == 0)
  const size_t sA1 = (size_t)KU;         // row stride of A1 source
  const ushort_t* __restrict__ WU = Wt + ((l == 0) ? OFF_U0 : OFF_UL(l));
  const ushort_t* __restrict__ WV = Wt + ((l == 0) ? OFF_V0 : OFF_VL(l));

  // gate-phase constants (persistent)
  const int gm = tid >> 2;               // batch row 0..63
  const int gq = (tid & 3) << 1;         // col pair 0,2,4,6
  const int gcol = hcol0 + gq;
  const float* __restrict__ bias = (l == 0) ? b0 : (bL + (size_t)(l - 1) * NG_);
  const f32x2 bi = *(const f32x2*)(bias + gcol);
  const f32x2 bff = *(const f32x2*)(bias + 1024 + gcol);
  const f32x2 bg = *(const f32x2*)(bias + 2048 + gcol);
  const f32x2 bo = *(const f32x2*)(bias + 3072 + gcol);
  const size_t cbase = ((size_t)l * B_ + gm) * H_ + gcol;
  f32x2 creg = (f32x2){0.f, 0.f};        // cell state lives in registers
  int* __restrict__ myflag = flags + l * S_;

  for (int t = 0; t < S_; ++t) {
    // true-dependency gates (device-scope acquire)
    if (l > 0) waitflag(flags + (l - 1) * S_ + t);
    if (t > 0) waitflag(myflag + (t - 1));
    if (l < L_ - 1 && t >= 4) waitflag(flags + (l + 1) * S_ + (t - 4));

    const ushort_t* __restrict__ A1 =
        (l == 0) ? (xb + (size_t)t * (B_ * IN_))
                 : (hring + (size_t)(t & 3) * (L_ * B_ * H_) +
                    (size_t)(l - 1) * (B_ * H_));
    const ushort_t* __restrict__ A2 =
        hring + (size_t)((t - 1) & 3) * (L_ * B_ * H_) + (size_t)l * (B_ * H_);

    auto stage = [&](int c) {
      const ushort_t* Ab; size_t sAs; const ushort_t* Wb; size_t Ks; int cb;
      if (c < nU) { Ab = A1; sAs = sA1; Wb = WU; Ks = (size_t)KU; cb = c << 6; }
      else        { Ab = A2; sAs = (size_t)H_; Wb = WV; Ks = (size_t)H_; cb = (c - nU) << 6; }
      ushort_t* rb = &ring[c & 3][0];
      {
        const int g = (w << 6) + lane;          // W unit 0..255
        const int wr = g >> 3;
        const int us = (g & 7) ^ (wr & 7);      // inverse swizzle on source
        const int ng = ((wr >> 3) << 10) + hcol0 + (wr & 7);
        gload_lds(Wb + (size_t)ng * Ks + cb + (us << 3), rb + (w << 9));
      }
#pragma unroll
      for (int i = 0; i < 2; ++i) {
        const int g = (w << 7) + (i << 6) + lane;   // A unit 0..511
        const int ar = g >> 3;
        const int us = (g & 7) ^ (ar & 7);
        gload_lds(Ab + (size_t)ar * sAs + cb + (us << 3),
                  rb + 2048 + (w << 10) + (i << 9));
      }
    };

    stage(0); stage(1); stage(2);

    f32x4 acc[2];
    acc[0] = (f32x4){0.f, 0.f, 0.f, 0.f};
    acc[1] = (f32x4){0.f, 0.f, 0.f, 0.f};

    for (int c = 0; c < nch; ++c) {
      if (c + 2 < nch) WAITV6(); else if (c + 1 < nch) WAITV3(); else WAITV0();
      BAR();                       // publish chunk c; retire buf c-3 reads
      if (c + 3 < nch) stage(c + 3);
      const ushort_t* rb = &ring[c & 3][0];
#pragma unroll
      for (int ks = 0; ks < 2; ++ks) {
        const int u = ((ks << 2) + kg) ^ (l15 & 7);
        bf16x8 av = *(const bf16x8*)(rb + 2048 + ((w << 4) + l15) * 64 + (u << 3));
        bf16x8 w0 = *(const bf16x8*)(rb + l15 * 64 + (u << 3));
        bf16x8 w1 = *(const bf16x8*)(rb + (16 + l15) * 64 + (u << 3));
        acc[0] = MFMA16(av, w0, acc[0]);
        acc[1] = MFMA16(av, w1, acc[1]);
      }
    }

    // D layout: within fragment, col = l15, row = kg*4 + j
    const int g0 = l15 >> 3, c7 = l15 & 7;
#pragma unroll
    for (int nf = 0; nf < 2; ++nf)
#pragma unroll
      for (int j = 0; j < 4; ++j)
        zsb[(((nf * 2 + g0) << 6) + (w << 4) + (kg << 2) + j) * 10 + c7] = acc[nf][j];
    __syncthreads();

    // ---- gate phase: 64 rows x 8 cols, 2 per thread ----
    {
      f32x2 zi = *(const f32x2*)&zsb[((0 << 6) + gm) * 10 + gq] + bi;
      f32x2 zf = *(const f32x2*)&zsb[((1 << 6) + gm) * 10 + gq] + bff;
      f32x2 zg = *(const f32x2*)&zsb[((2 << 6) + gm) * 10 + gq] + bg;
      f32x2 zo = *(const f32x2*)&zsb[((3 << 6) + gm) * 10 + gq] + bo;
      f32x2 hv;
#pragma unroll
      for (int j = 0; j < 2; ++j) {
        float iv = 1.f / (1.f + expf(-zi[j]));
        float fv = 1.f / (1.f + expf(-zf[j]));
        float gv = tanhf(zg[j]);
        float ov = 1.f / (1.f + expf(-zo[j]));
        float cn = fv * creg[j] + iv * gv;
        creg[j] = cn;
        hv[j] = ov * tanhf(cn);
      }
      unsigned hb2 = (unsigned)f2bf(hv[0]) | (((unsigned)f2bf(hv[1])) << 16);
      *(unsigned*)(hring + (size_t)(t & 3) * (L_ * B_ * H_) +
                   (size_t)l * (B_ * H_) + (size_t)gm * H_ + gcol) = hb2;
      if (l == L_ - 1)
        *(f32x2*)(seq + ((size_t)gm * S_ + t) * H_ + gcol) = hv;
      if (t == S_ - 1) {
        *(f32x2*)(cf + cbase) = creg;
        *(f32x2*)(hf + cbase) = hv;
      }
    }
    __syncthreads();               // drains stores; zs reads done before reuse
    if (tid == 0) {
      __threadfence();
      __hip_atomic_fetch_add(myflag + t, 1, __ATOMIC_RELEASE,
                             __HIP_MEMORY_SCOPE_AGENT);
    }
  }
}

// ============== fallback: R5 grid.sync version (known-good) ==============
__global__ void __launch_bounds__(256)
k_lstm_sync(const ushort_t* __restrict__ xb,
            const ushort_t* __restrict__ Wt,
            const float* __restrict__ b0,
            const float* __restrict__ bL,
            ushort_t* __restrict__ hbf,
            float* __restrict__ out) {
  cooperative_groups::grid_group grid = cooperative_groups::this_grid();
  float* __restrict__ seq = out;
  float* __restrict__ hf = out + (size_t)B_ * S_ * H_;
  float* __restrict__ cf = hf + (size_t)L_ * B_ * H_;
  __shared__ ushort_t sW[3][2048];
  __shared__ ushort_t sA[3][4096];
  __shared__ float zs[4][64][10];

  const int tid = threadIdx.x;
  const int w = tid >> 6;
  const int lane = tid & 63;
  const int l15 = lane & 15;
  const int kg = lane >> 4;
  const int wg = blockIdx.x;
  const int nwg = gridDim.x;

  for (int T = 0; T < NTICK; ++T) {
    const ushort_t* __restrict__ hprev = hbf + (size_t)((T + 1) & 1) * (L_ * B_ * H_);
    ushort_t* __restrict__ hcur = hbf + (size_t)(T & 1) * (L_ * B_ * H_);
    for (int task = wg; task < NWGF; task += nwg) {
      const int l = task >> 7;
      const int jb = task & 127;
      const int t = T - l;
      if (t < 0 || t >= S_) continue;
      const int hcol0 = jb << 3;
      const int K1 = (l == 0) ? IN_ : H_;
      const int nU = K1 >> 6;
      const int nch = nU + (H_ >> 6);
      const size_t sA1 = (l == 0) ? (size_t)IN_ : (size_t)H_;
      const ushort_t* __restrict__ A1 =
          (l == 0) ? (xb + (size_t)t * (B_ * IN_))
                   : (hprev + (size_t)(l - 1) * (B_ * H_));
      const ushort_t* __restrict__ A2 = hprev + (size_t)l * (B_ * H_);
      const ushort_t* __restrict__ WU = Wt + ((l == 0) ? OFF_U0 : OFF_UL(l));
      const ushort_t* __restrict__ WV = Wt + ((l == 0) ? OFF_V0 : OFF_VL(l));

      const int gm = tid >> 2;
      const int gq = (tid & 3) << 1;
      const int gcol = hcol0 + gq;
      const size_t cbase = ((size_t)l * B_ + gm) * H_ + gcol;
      const float* __restrict__ bias = (l == 0) ? b0 : (bL + (size_t)(l - 1) * NG_);
      f32x2 bi = *(const f32x2*)(bias + gcol);
      f32x2 bff = *(const f32x2*)(bias + 1024 + gcol);
      f32x2 bg = *(const f32x2*)(bias + 2048 + gcol);
      f32x2 bo = *(const f32x2*)(bias + 3072 + gcol);
      f32x2 cold = (f32x2){0.f, 0.f};
      if (t > 0) cold = *(const f32x2*)(cf + cbase);

      auto stage = [&](int c) {
        const ushort_t* Ab; size_t sAs; const ushort_t* Wb; size_t Ks; int cb;
        if (c < nU) { Ab = A1; sAs = sA1; Wb = WU; Ks = (size_t)K1; cb = c << 6; }
        else        { Ab = A2; sAs = (size_t)H_; Wb = WV; Ks = (size_t)H_; cb = (c - nU) << 6; }
        const int buf = c % 3;
        {
          const int g = (w << 6) + lane;
          const int wr = g >> 3;
          const int us = (g & 7) ^ (wr & 7);
          const int ng = ((wr >> 3) << 10) + hcol0 + (wr & 7);
          gload_lds(Wb + (size_t)ng * Ks + cb + (us << 3), &sW[buf][w << 9]);
        }
#pragma unroll
        for (int i = 0; i < 2; ++i) {
          const int g = (w << 7) + (i << 6) + lane;
          const int ar = g >> 3;
          const int us = (g & 7) ^ (ar & 7);
          gload_lds(Ab + (size_t)ar * sAs + cb + (us << 3),
                    &sA[buf][(w << 10) + (i << 9)]);
        }
      };

      stage(0); stage(1);
      f32x4 acc[2];
      acc[0] = (f32x4){0.f, 0.f, 0.f, 0.f};
      acc[1] = (f32x4){0.f, 0.f, 0.f, 0.f};
      for (int c = 0; c < nch; ++c) {
        if (c + 1 < nch) WAITV3(); else WAITV0();
        BAR();
        if (c + 2 < nch) stage(c + 2);
        const int buf = c % 3;
        const ushort_t* sa = sA[buf];
        const ushort_t* sw = sW[buf];
#pragma unroll
        for (int ks = 0; ks < 2; ++ks) {
          const int u = ((ks << 2) + kg) ^ (l15 & 7);
          bf16x8 av = *(const bf16x8*)(sa + ((w << 4) + l15) * 64 + (u << 3));
          bf16x8 w0 = *(const bf16x8*)(sw + l15 * 64 + (u << 3));
          bf16x8 w1 = *(const bf16x8*)(sw + (16 + l15) * 64 + (u << 3));
          acc[0] = MFMA16(av, w0, acc[0]);
          acc[1] = MFMA16(av, w1, acc[1]);
        }
      }
      const int g0 = l15 >> 3, c7 = l15 & 7;
#pragma unroll
      for (int nf = 0; nf < 2; ++nf)
#pragma unroll
        for (int j = 0; j < 4; ++j)
          zs[nf * 2 + g0][(w << 4) + (kg << 2) + j][c7] = acc[nf][j];
      __syncthreads();
      {
        f32x2 zi = *(const f32x2*)&zs[0][gm][gq] + bi;
        f32x2 zf = *(const f32x2*)&zs[1][gm][gq] + bff;
        f32x2 zg = *(const f32x2*)&zs[2][gm][gq] + bg;
        f32x2 zo = *(const f32x2*)&zs[3][gm][gq] + bo;
        f32x2 cnew, hv;
#pragma unroll
        for (int j = 0; j < 2; ++j) {
          float iv = 1.f / (1.f + expf(-zi[j]));
          float fv = 1.f / (1.f + expf(-zf[j]));
          float gv = tanhf(zg[j]);
          float ov = 1.f / (1.f + expf(-zo[j]));
          float cn = fv * cold[j] + iv * gv;
          cnew[j] = cn;
          hv[j] = ov * tanhf(cn);
        }
        *(f32x2*)(cf + cbase) = cnew;
        *(f32x2*)(hf + cbase) = hv;
        unsigned hb2 = (unsigned)f2bf(hv[0]) | (((unsigned)f2bf(hv[1])) << 16);
        *(unsigned*)(hcur + (size_t)l * (B_ * H_) + (size_t)gm * H_ + gcol) = hb2;
        if (l == L_ - 1)
          *(f32x2*)(seq + ((size_t)gm * S_ + t) * H_ + gcol) = hv;
      }
      __syncthreads();
    }
    grid.sync();
  }
}

extern "C" void kernel_launch(void* const* d_in, const int* in_sizes, int n_in,
                              void* d_out, int out_size, void* d_ws, size_t ws_size,
                              hipStream_t stream) {
  const float* x = (const float*)d_in[0];
  const float* U0 = (const float*)d_in[1];
  const float* V0 = (const float*)d_in[2];
  const float* b0 = (const float*)d_in[3];
  const float* U = (const float*)d_in[4];
  const float* V = (const float*)d_in[5];
  const float* bL = (const float*)d_in[6];
  float* out = (float*)d_out;

  char* ws = (char*)d_ws;
  unsigned short* Wt = (unsigned short*)ws;
  unsigned short* xb = (unsigned short*)(ws + WT_BYTES);
  unsigned short* hring = (unsigned short*)(ws + WT_BYTES + XB_BYTES);
  int* flags = (int*)(ws + WT_BYTES + XB_BYTES + HRING_BYTES);

  dim3 tb(32, 8);
  hipLaunchKernelGGL(k_transpose_bf16, dim3(128, 16), tb, 0, stream, U0, Wt + OFF_U0, 512, 4096);
  hipLaunchKernelGGL(k_transpose_bf16, dim3(128, 32), tb, 0, stream, V0, Wt + OFF_V0, 1024, 4096);
  for (int l = 1; l < 6; ++l) {
    hipLaunchKernelGGL(k_transpose_bf16, dim3(128, 32), tb, 0, stream,
                       U + (size_t)(l - 1) * 4194304ul, Wt + OFF_UL(l), 1024, 4096);
    hipLaunchKernelGGL(k_transpose_bf16, dim3(128, 32), tb, 0, stream,
                       V + (size_t)(l - 1) * 4194304ul, Wt + OFF_VL(l), 1024, 4096);
  }
  hipLaunchKernelGGL(k_cvt_x, dim3(S_, B_), dim3(128), 0, stream, x, xb);
  hipMemsetAsync(hring, 0, HRING_BYTES, stream);
  hipMemsetAsync(flags, 0, FLAGS_BYTES, stream);

  // Primary: flag-sync dataflow kernel. Cooperative launch purely for the
  // co-residency validation (all 768 WGs must be resident or it deadlocks).
  void* args[] = { (void*)&xb, (void*)&Wt, (void*)&b0, (void*)&bL,
                   (void*)&hring, (void*)&flags, (void*)&out };
  hipError_t e = hipLaunchCooperativeKernel((void*)k_lstm_flag, dim3(NWGF),
                                            dim3(256), args, 0, stream);
  if (e != hipSuccess) {
    (void)hipGetLastError();  // clear sticky error; use known-good fallback
    int maxB = 0;
    hipOccupancyMaxActiveBlocksPerMultiprocessor(&maxB, k_lstm_sync, 256, 0);
    int nwg = maxB * 256;
    if (nwg > NWGF) nwg = NWGF;
    if (nwg < 256) nwg = 256;
    void* args2[] = { (void*)&xb, (void*)&Wt, (void*)&b0, (void*)&bL,
                      (void*)&hring, (void*)&out };
    hipLaunchCooperativeKernel((void*)k_lstm_sync, dim3(nwg), dim3(256),
                               args2, 0, stream);
  }
}

// Round 7
// 23831.046 us; speedup vs baseline: 1.9349x; 1.9349x over previous
//
#include <hip/hip_runtime.h>
#include <hip/hip_cooperative_groups.h>

#define B_ 64
#define H_ 1024
#define IN_ 512
#define S_ 256
#define L_ 6
#define NG_ 4096
#define NTASK 768            // 6 layers * 128 col-slices (8 H-cols x 4 gates)
#define NTICK (S_ + L_ - 1)

typedef __bf16 bf16x8 __attribute__((ext_vector_type(8)));
typedef float f32x4 __attribute__((ext_vector_type(4)));
typedef float f32x2 __attribute__((ext_vector_type(2)));
typedef unsigned short ushort8v __attribute__((ext_vector_type(8)));
typedef unsigned short ushort_t;

// ws layout (ushort elems): Wp panels 48,234,496 | xb 8,388,608 | hbf 786,432
#define WP_BYTES 96468992ul
#define XB_BYTES 16777216ul
#define HBF_ELEMS 786432ul          // 2 slots * L * 65536
#define LSLOT 65536ul               // one layer's packed h (64x1024 bf16)
#define XSLOT 32768ul               // one timestep's packed x (64x512 bf16)
// panel offset: l==0 panels are 49152 elems (48 ks), l>0 are 65536 (64 ks)
__host__ __device__ __forceinline__ size_t poff(int l, int jb) {
  return (l == 0) ? (size_t)jb * 49152ul
                  : 6291456ul + ((size_t)(l - 1) * 128 + jb) * 65536ul;
}

#define MFMA16(a, b, c) __builtin_amdgcn_mfma_f32_16x16x32_bf16(a, b, c, 0, 0, 0)
#define BAR() __builtin_amdgcn_s_barrier()
#define WAITV3() asm volatile("s_waitcnt vmcnt(3)" ::: "memory")
#define WAITV0() asm volatile("s_waitcnt vmcnt(0)" ::: "memory")

__device__ __forceinline__ unsigned short f2bf(float f) {
  union { float f; unsigned u; } v; v.f = f;
  unsigned r = v.u + 0x7fffu + ((v.u >> 16) & 1u);
  return (unsigned short)(r >> 16);
}

__device__ __forceinline__ void gload_lds(const ushort_t* g, ushort_t* l) {
  __builtin_amdgcn_global_load_lds(
      (const __attribute__((address_space(1))) unsigned int*)g,
      (__attribute__((address_space(3))) unsigned int*)l, 16, 0, 0);
}

// ---- one-time weight pack: per-(l,jb) panel in MFMA-fragment order ----
// unit (ks,f,lane) 16B: W[k][n], k = ks*32 + (lane>>4)*8 + e,
// n = (f*2 + ((lane&15)>>3))*1024 + jb*8 + (lane&7)
__global__ void k_pack_w(const float* __restrict__ U0, const float* __restrict__ V0,
                         const float* __restrict__ U, const float* __restrict__ V,
                         ushort_t* __restrict__ Wp) {
  __shared__ float tile[32][33];
  const int bx = blockIdx.x;
  const int l = bx >> 7, jb = bx & 127;
  ushort_t* __restrict__ panel = Wp + poff(l, jb);
  const int nksU = ((l == 0) ? IN_ : H_) >> 5;
  const int t = threadIdx.x;
  for (int part = 0; part < 2; ++part) {
    const float* __restrict__ W =
        (l == 0) ? (part ? V0 : U0)
                 : (part ? V + (size_t)(l - 1) * H_ * NG_
                         : U + (size_t)(l - 1) * H_ * NG_);
    const int nks = part ? (H_ >> 5) : nksU;
    const int ksbase = part ? nksU : 0;
    for (int ks = 0; ks < nks; ++ks) {
      {
        const int kr = t >> 3, g = (t & 7) >> 1, half = t & 1;
        float4 v = *(const float4*)(W + (size_t)(ks * 32 + kr) * NG_ +
                                    g * 1024 + jb * 8 + half * 4);
        tile[kr][g * 8 + half * 4 + 0] = v.x;
        tile[kr][g * 8 + half * 4 + 1] = v.y;
        tile[kr][g * 8 + half * 4 + 2] = v.z;
        tile[kr][g * 8 + half * 4 + 3] = v.w;
      }
      __syncthreads();
      if (t < 128) {
        const int f = t >> 6, lane = t & 63;
        const int gate = f * 2 + ((lane & 15) >> 3);
        const int kg8 = (lane >> 4) * 8;
        const int nloc = gate * 8 + (lane & 7);
        ushort8v u;
#pragma unroll
        for (int e = 0; e < 8; ++e) u[e] = f2bf(tile[kg8 + e][nloc]);
        *(ushort8v*)(panel + (((size_t)(ksbase + ks) * 2 + f) * 64 + lane) * 8) = u;
      }
      __syncthreads();
    }
  }
}

// ---- one-time x -> bf16 in A-fragment order, per timestep ----
// unit (ks, w, lane): row b = w*16 + (lane&15), k = ks*32 + (lane>>4)*8 + e
__global__ void k_cvt_x(const float* __restrict__ x, ushort_t* __restrict__ xb) {
  const int tt = blockIdx.x;
  const int tid = threadIdx.x;
  const int b = tid >> 2, kq = (tid & 3) << 7;
  const float* __restrict__ src = x + ((size_t)b * S_ + tt) * IN_ + kq;
  ushort_t* __restrict__ dst = xb + (size_t)tt * XSLOT;
  const int w = b >> 4, l15 = b & 15;
#pragma unroll
  for (int kk = 0; kk < 128; kk += 8) {
    float4 v0 = *(const float4*)(src + kk);
    float4 v1 = *(const float4*)(src + kk + 4);
    ushort8v u = { f2bf(v0.x), f2bf(v0.y), f2bf(v0.z), f2bf(v0.w),
                   f2bf(v1.x), f2bf(v1.y), f2bf(v1.z), f2bf(v1.w) };
    const int k = kq + kk;
    const int ks = k >> 5, kg = (k & 31) >> 3;
    *(ushort8v*)(dst + (((size_t)ks * 4 + w) * 64 + kg * 16 + l15) * 8) = u;
  }
}

__global__ void __launch_bounds__(256)
k_lstm(const ushort_t* __restrict__ xb,
       const ushort_t* __restrict__ Wp,
       const float* __restrict__ b0,
       const float* __restrict__ bL,
       ushort_t* __restrict__ hbf,   // [2][L][LSLOT] packed bf16, pre-zeroed
       float* __restrict__ out) {
  cooperative_groups::grid_group grid = cooperative_groups::this_grid();
  float* __restrict__ seq = out;                           // [B][S][H]
  float* __restrict__ hf = out + (size_t)B_ * S_ * H_;     // [L][B][H]
  float* __restrict__ cf = hf + (size_t)L_ * B_ * H_;      // [L][B][H]

  __shared__ __align__(16) ushort_t sW[3][2048];  // chunk: 4 x 1KB fragment blocks
  __shared__ __align__(16) ushort_t sA[3][4096];  // chunk: 8 x 1KB fragment blocks
  __shared__ float zs[4][64][10];

  const int tid = threadIdx.x;
  const int w = tid >> 6;        // wave: A-rows w*16..w*16+15
  const int lane = tid & 63;
  const int l15 = lane & 15;
  const int wg = blockIdx.x;
  const int nwg = gridDim.x;

  for (int T = 0; T < NTICK; ++T) {
    const ushort_t* __restrict__ hprev = hbf + (size_t)((T + 1) & 1) * (L_ * LSLOT);
    ushort_t* __restrict__ hcur = hbf + (size_t)(T & 1) * (L_ * LSLOT);

    for (int task = wg; task < NTASK; task += nwg) {
      const int l = task >> 7;
      const int jb = task & 127;
      const int t = T - l;
      if (t < 0 || t >= S_) continue;

      const int hcol0 = jb << 3;
      const int nU = ((l == 0) ? IN_ : H_) >> 6;   // chunks in the U part
      const int nch = nU + (H_ >> 6);              // 24 or 32
      const ushort_t* __restrict__ panel = Wp + poff(l, jb);
      const ushort_t* __restrict__ A1 =
          (l == 0) ? (xb + (size_t)t * XSLOT) : (hprev + (size_t)(l - 1) * LSLOT);
      const ushort_t* __restrict__ A2 = hprev + (size_t)l * LSLOT;

      // gate-phase operands (issued early; compiler may sink them - fine)
      const int gm = tid >> 2;
      const int gq = (tid & 3) << 1;
      const int gcol = hcol0 + gq;
      const size_t cbase = ((size_t)l * B_ + gm) * H_ + gcol;
      const float* __restrict__ bias = (l == 0) ? b0 : (bL + (size_t)(l - 1) * NG_);
      f32x2 bi = *(const f32x2*)(bias + gcol);
      f32x2 bff = *(const f32x2*)(bias + 1024 + gcol);
      f32x2 bg = *(const f32x2*)(bias + 2048 + gcol);
      f32x2 bo = *(const f32x2*)(bias + 3072 + gcol);
      f32x2 cold = (f32x2){0.f, 0.f};
      if (t > 0) cold = *(const f32x2*)(cf + cbase);

      // ---- staging: 3 contiguous 1KB global_load_lds per wave per chunk ----
      auto stage = [&](int c) {
        const int buf = c % 3;
        gload_lds(panel + ((size_t)(4 * c + w)) * 512 + lane * 8,
                  &sW[buf][(size_t)w * 512]);
        const ushort_t* Asrc; int cb;
        if (c < nU) { Asrc = A1; cb = c; } else { Asrc = A2; cb = c - nU; }
        gload_lds(Asrc + ((size_t)(8 * cb + w)) * 512 + lane * 8,
                  &sA[buf][(size_t)w * 512]);
        gload_lds(Asrc + ((size_t)(8 * cb + 4 + w)) * 512 + lane * 8,
                  &sA[buf][(size_t)(4 + w) * 512]);
      };

      stage(0); stage(1);

      f32x4 acc[2];
      acc[0] = (f32x4){0.f, 0.f, 0.f, 0.f};
      acc[1] = (f32x4){0.f, 0.f, 0.f, 0.f};

      for (int c = 0; c < nch; ++c) {
        if (c + 1 < nch) WAITV3(); else WAITV0();
        BAR();                       // publish chunk c; retire buf c-1 reads
        if (c + 2 < nch) stage(c + 2);
        const ushort_t* sa = sA[c % 3];
        const ushort_t* sw = sW[c % 3];
#pragma unroll
        for (int ks2 = 0; ks2 < 2; ++ks2) {
          bf16x8 av = *(const bf16x8*)(sa + ((ks2 * 4 + w) * 64 + lane) * 8);
          bf16x8 w0 = *(const bf16x8*)(sw + ((ks2 * 2) * 64 + lane) * 8);
          bf16x8 w1 = *(const bf16x8*)(sw + ((ks2 * 2 + 1) * 64 + lane) * 8);
          acc[0] = MFMA16(av, w0, acc[0]);
          acc[1] = MFMA16(av, w1, acc[1]);
        }
      }

      // D layout: within fragment, col = l15, row = (lane>>4)*4 + j
      const int g0 = l15 >> 3, c7 = l15 & 7;
      const int kg = lane >> 4;
#pragma unroll
      for (int nf = 0; nf < 2; ++nf)
#pragma unroll
        for (int j = 0; j < 4; ++j)
          zs[nf * 2 + g0][(w << 4) + (kg << 2) + j][c7] = acc[nf][j];
      __syncthreads();

      // ---- gate phase: 64 rows x 8 cols, 2 per thread ----
      {
        f32x2 zi = *(const f32x2*)&zs[0][gm][gq] + bi;
        f32x2 zf = *(const f32x2*)&zs[1][gm][gq] + bff;
        f32x2 zg = *(const f32x2*)&zs[2][gm][gq] + bg;
        f32x2 zo = *(const f32x2*)&zs[3][gm][gq] + bo;
        f32x2 cnew, hv;
#pragma unroll
        for (int j = 0; j < 2; ++j) {
          float iv = 1.f / (1.f + expf(-zi[j]));
          float fv = 1.f / (1.f + expf(-zf[j]));
          float gv = tanhf(zg[j]);
          float ov = 1.f / (1.f + expf(-zo[j]));
          float cn = fv * cold[j] + iv * gv;
          cnew[j] = cn;
          hv[j] = ov * tanhf(cn);
        }
        *(f32x2*)(cf + cbase) = cnew;
        // h write in packed A-fragment layout
        const int hw = gm >> 4, hl15 = gm & 15;
        const int hks = gcol >> 5, hkg = (gcol & 31) >> 3, he = gcol & 7;
        unsigned hb2 = (unsigned)f2bf(hv[0]) | (((unsigned)f2bf(hv[1])) << 16);
        *(unsigned*)(hcur + (size_t)l * LSLOT +
                     (((size_t)hks * 4 + hw) * 64 + hkg * 16 + hl15) * 8 + he) = hb2;
        if (l == L_ - 1)
          *(f32x2*)(seq + ((size_t)gm * S_ + t) * H_ + gcol) = hv;
        if (t == S_ - 1)
          *(f32x2*)(hf + cbase) = hv;
      }
      __syncthreads(); // zs safe before next task reuses it
    }
    grid.sync();
  }
}

extern "C" void kernel_launch(void* const* d_in, const int* in_sizes, int n_in,
                              void* d_out, int out_size, void* d_ws, size_t ws_size,
                              hipStream_t stream) {
  const float* x = (const float*)d_in[0];
  const float* U0 = (const float*)d_in[1];
  const float* V0 = (const float*)d_in[2];
  const float* b0 = (const float*)d_in[3];
  const float* U = (const float*)d_in[4];
  const float* V = (const float*)d_in[5];
  const float* bL = (const float*)d_in[6];
  float* out = (float*)d_out;

  char* ws = (char*)d_ws;
  unsigned short* Wp = (unsigned short*)ws;
  unsigned short* xb = (unsigned short*)(ws + WP_BYTES);
  unsigned short* hbf = (unsigned short*)(ws + WP_BYTES + XB_BYTES);

  hipLaunchKernelGGL(k_pack_w, dim3(NTASK), dim3(256), 0, stream, U0, V0, U, V, Wp);
  hipLaunchKernelGGL(k_cvt_x, dim3(S_), dim3(256), 0, stream, x, xb);
  hipMemsetAsync(hbf, 0, HBF_ELEMS * 2, stream);

  int maxB = 0;
  hipOccupancyMaxActiveBlocksPerMultiprocessor(&maxB, k_lstm, 256, 0);
  int nwg = maxB * 256;
  if (nwg > NTASK) nwg = NTASK;
  if (nwg < 256) nwg = 256;

  void* args[] = { (void*)&xb, (void*)&Wp, (void*)&b0, (void*)&bL,
                   (void*)&hbf, (void*)&out };
  hipLaunchCooperativeKernel((void*)k_lstm, dim3(nwg), dim3(256), args, 0, stream);
}

// Round 9
// 16844.814 us; speedup vs baseline: 2.7374x; 1.4147x over previous
//
#include <hip/hip_runtime.h>
#include <hip/hip_cooperative_groups.h>

#define B_ 64
#define H_ 1024
#define IN_ 512
#define S_ 256
#define L_ 6
#define NG_ 4096
#define NTASK 768            // 6 cells * 128 col-slices (8 H-cols x 4 gates)
#define NTICK (S_ + L_ - 1)

typedef __bf16 bf16x8 __attribute__((ext_vector_type(8)));
typedef float f32x4 __attribute__((ext_vector_type(4)));
typedef unsigned short ushort8v __attribute__((ext_vector_type(8)));
typedef unsigned short ushort_t;

#define WP_BYTES 96468992ul
#define XB_BYTES 16777216ul
#define HBF_ELEMS 786432ul          // 2 slots * L * 65536
#define LSLOT 65536ul               // packed h per layer (64 rows x 1024 K)
#define XSLOT 32768ul               // packed x per timestep (64 x 512)

// panel per (l,jb): chunk-major units (c*4 + nf*2 + ks) of 512 ushorts
__host__ __device__ __forceinline__ size_t poff(int l, int jb) {
  return (l == 0) ? (size_t)jb * 49152ul
                  : 6291456ul + ((size_t)(l - 1) * 128 + jb) * 65536ul;
}

#define MFMA16(a, b, c) __builtin_amdgcn_mfma_f32_16x16x32_bf16(a, b, c, 0, 0, 0)
#define WAITN(n) asm volatile("s_waitcnt vmcnt(" #n ")" ::: "memory")

__device__ __forceinline__ unsigned short f2bf(float f) {
  union { float f; unsigned u; } v; v.f = f;
  unsigned r = v.u + 0x7fffu + ((v.u >> 16) & 1u);
  return (unsigned short)(r >> 16);
}

// ---- one-time weight pack: unit (c, nf, ks), lane, e:
// W[k][n], k = c*64 + ks*32 + (lane>>4)*8 + e,
// n = (nf*2 + ((lane&15)>>3))*1024 + jb*8 + (lane&7); V part at k >= KU.
__global__ void k_pack_w(const float* __restrict__ U0, const float* __restrict__ V0,
                         const float* __restrict__ U, const float* __restrict__ V,
                         ushort_t* __restrict__ Wp) {
  const int bx = blockIdx.x;              // 0..767
  const int l = bx >> 7, jb = bx & 127;
  ushort_t* __restrict__ panel = Wp + poff(l, jb);
  const int KU = (l == 0) ? IN_ : H_;
  const int NU = KU >> 6;
  const int NCH = NU + 16;
  const float* __restrict__ Usrc = (l == 0) ? U0 : U + (size_t)(l - 1) * H_ * NG_;
  const float* __restrict__ Vsrc = (l == 0) ? V0 : V + (size_t)(l - 1) * H_ * NG_;
  const int t = threadIdx.x, lane = t & 63, g4 = t >> 6;
  const int l15 = lane & 15, kg = lane >> 4;
  for (int p = 0; p < NCH; ++p) {
    const int gi = p * 4 + g4;
    const int c = gi >> 2, u = gi & 3, nf = u >> 1, ks = u & 1;
    const int n = (nf * 2 + (l15 >> 3)) * 1024 + jb * 8 + (l15 & 7);
    const int k = c * 64 + ks * 32 + kg * 8;
    const float* __restrict__ src =
        (c < NU) ? (Usrc + (size_t)k * NG_ + n)
                 : (Vsrc + (size_t)(k - KU) * NG_ + n);
    ushort8v uv;
#pragma unroll
    for (int e = 0; e < 8; ++e) uv[e] = f2bf(src[(size_t)e * NG_]);
    *(ushort8v*)(panel + (size_t)gi * 512 + lane * 8) = uv;
  }
}

// ---- one-time x -> bf16 in packed-A unit order, per timestep ----
__global__ void k_cvt_x(const float* __restrict__ x, ushort_t* __restrict__ xb) {
  const int tt = blockIdx.x;
  const int tid = threadIdx.x;
  const int b = tid >> 2, kq = (tid & 3) << 7;
  const float* __restrict__ src = x + ((size_t)b * S_ + tt) * IN_ + kq;
  ushort_t* __restrict__ dst = xb + (size_t)tt * XSLOT;
  const int w = b >> 4, l15 = b & 15;
#pragma unroll
  for (int kk = 0; kk < 128; kk += 8) {
    float4 v0 = *(const float4*)(src + kk);
    float4 v1 = *(const float4*)(src + kk + 4);
    ushort8v u = { f2bf(v0.x), f2bf(v0.y), f2bf(v0.z), f2bf(v0.w),
                   f2bf(v1.x), f2bf(v1.y), f2bf(v1.z), f2bf(v1.w) };
    const int k = kq + kk;
    const int ks = k >> 5, kg = (k & 31) >> 3;
    *(ushort8v*)(dst + (((size_t)ks * 4 + w) * 64 + kg * 16 + l15) * 8) = u;
  }
}

// Per-wave GEMM over K: 16 rows x 32 N-cols, all operands VGPR-direct.
// 4 register banks, lookahead 3, counted vmcnt fences pin the issue order.
template<int NCH>
__device__ __forceinline__ void gemm_tick(f32x4 acc[2],
                                          const ushort_t* __restrict__ panel,
                                          const ushort_t* __restrict__ A1,
                                          const ushort_t* __restrict__ A2,
                                          int w, int lane) {
  constexpr int NU = NCH - 16;
  bf16x8 Wb[4][4];
  bf16x8 Ab[4][2];
#define LDU(p) (*(const bf16x8*)(p))
#define ISSUE(c) do { \
    const ushort_t* wp_ = panel + (size_t)(c) * 2048 + lane * 8; \
    Wb[(c) & 3][0] = LDU(wp_); \
    Wb[(c) & 3][1] = LDU(wp_ + 512); \
    Wb[(c) & 3][2] = LDU(wp_ + 1024); \
    Wb[(c) & 3][3] = LDU(wp_ + 1536); \
    const ushort_t* ap_ = ((c) < NU \
        ? A1 + ((size_t)(2 * (c)) * 4 + w) * 512 \
        : A2 + ((size_t)(2 * ((c) - NU)) * 4 + w) * 512) + lane * 8; \
    Ab[(c) & 3][0] = LDU(ap_); \
    Ab[(c) & 3][1] = LDU(ap_ + 2048); \
  } while (0)
  ISSUE(0); ISSUE(1); ISSUE(2);
#pragma unroll
  for (int c = 0; c < NCH; ++c) {
    if (c + 3 < NCH) ISSUE(c + 3);
    const int rem = NCH - 1 - c;
    if (rem >= 3) { WAITN(18); }
    else if (rem == 2) { WAITN(12); }
    else if (rem == 1) { WAITN(6); }
    else { WAITN(0); }
    acc[0] = MFMA16(Ab[c & 3][0], Wb[c & 3][0], acc[0]);  // ks0 nf0
    acc[1] = MFMA16(Ab[c & 3][0], Wb[c & 3][2], acc[1]);  // ks0 nf1
    acc[0] = MFMA16(Ab[c & 3][1], Wb[c & 3][1], acc[0]);  // ks1 nf0
    acc[1] = MFMA16(Ab[c & 3][1], Wb[c & 3][3], acc[1]);  // ks1 nf1
  }
#undef ISSUE
#undef LDU
}

__global__ void __launch_bounds__(256, 2)
k_lstm(const ushort_t* __restrict__ xb,
       const ushort_t* __restrict__ Wp,
       const float* __restrict__ b0,
       const float* __restrict__ bL,
       ushort_t* __restrict__ hbf,   // [2][L][LSLOT] packed bf16, pre-zeroed
       float* __restrict__ out, int multi) {
  cooperative_groups::grid_group grid = cooperative_groups::this_grid();
  float* __restrict__ seq = out;                           // [B][S][H]
  float* __restrict__ hf = out + (size_t)B_ * S_ * H_;     // [L][B][H]
  float* __restrict__ cf = hf + (size_t)L_ * B_ * H_;      // [L][B][H]
  __shared__ float hstF[512];   // 4 waves x 16 rows x 8 cols

  const int tid = threadIdx.x;
  const int w = tid >> 6;        // wave: rows w*16..w*16+15
  const int lane = tid & 63;
  const int l15 = lane & 15;
  const int kg = lane >> 4;
  const bool lo = (l15 < 8);
  const int wg = blockIdx.x;
  const int nwg = gridDim.x;

  float creg[4] = {0.f, 0.f, 0.f, 0.f};

  for (int T = 0; T < NTICK; ++T) {
    for (int task = wg; task < NTASK; task += nwg) {
      const int l = task >> 7;
      const int jb = task & 127;
      const int t = T - l;
      if (t < 0 || t >= S_) continue;
      const ushort_t* __restrict__ hprev = hbf + (size_t)((T + 1) & 1) * (L_ * LSLOT);
      ushort_t* __restrict__ hcur = hbf + (size_t)(T & 1) * (L_ * LSLOT);
      const ushort_t* __restrict__ panel = Wp + poff(l, jb);
      const ushort_t* __restrict__ A2 = hprev + (size_t)l * LSLOT;

      f32x4 acc[2];
      acc[0] = (f32x4){0.f, 0.f, 0.f, 0.f};
      acc[1] = (f32x4){0.f, 0.f, 0.f, 0.f};
      if (l == 0)
        gemm_tick<24>(acc, panel, xb + (size_t)t * XSLOT, A2, w, lane);
      else
        gemm_tick<32>(acc, panel, hprev + (size_t)(l - 1) * LSLOT, A2, w, lane);

      const int hc = (jb << 3) + (l15 & 7);
      const float* __restrict__ bias = (l == 0) ? b0 : (bL + (size_t)(l - 1) * NG_);
      const float bi = bias[hc];
      const float bfv = bias[1024 + hc];
      const float bgv = bias[2048 + hc];
      const float bov = bias[3072 + hc];

#pragma unroll
      for (int j = 0; j < 4; ++j) {
        float a0 = acc[0][j], a1 = acc[1][j];
        float p0 = __shfl_xor(a0, 8, 64);
        float p1 = __shfl_xor(a1, 8, 64);
        float zi = (lo ? a0 : p0) + bi;
        float zf = (lo ? p0 : a0) + bfv;
        float zg = (lo ? a1 : p1) + bgv;
        float zo = (lo ? p1 : a1) + bov;
        float iv = 1.f / (1.f + expf(-zi));
        float fv = 1.f / (1.f + expf(-zf));
        float gv = tanhf(zg);
        float ov = 1.f / (1.f + expf(-zo));
        const int r = w * 16 + kg * 4 + j;
        float cold;
        if (multi)
          cold = (t > 0) ? cf[((size_t)l * B_ + r) * H_ + hc] : 0.f;
        else
          cold = creg[j];
        float cn = fv * cold + iv * gv;
        creg[j] = cn;
        float hv = ov * tanhf(cn);
        if (lo) {
          hstF[w * 128 + (kg * 4 + j) * 8 + l15] = hv;
          if (multi || t == S_ - 1) cf[((size_t)l * B_ + r) * H_ + hc] = cn;
          if (t == S_ - 1) hf[((size_t)l * B_ + r) * H_ + hc] = hv;
        }
      }
      __syncthreads();
      if (kg == 0) {
        const int lr = l15;            // local row 0..15
        float4 v0 = *(const float4*)&hstF[w * 128 + lr * 8];
        float4 v1 = *(const float4*)&hstF[w * 128 + lr * 8 + 4];
        ushort8v u8 = { f2bf(v0.x), f2bf(v0.y), f2bf(v0.z), f2bf(v0.w),
                        f2bf(v1.x), f2bf(v1.y), f2bf(v1.z), f2bf(v1.w) };
        *(ushort8v*)(hcur + (size_t)l * LSLOT +
                     (((size_t)(jb >> 2) * 4 + w) * 64 + (jb & 3) * 16 + lr) * 8) = u8;
        if (l == L_ - 1) {
          float* sp = seq + (((size_t)(w * 16 + lr)) * S_ + t) * H_ + (jb << 3);
          *(float4*)sp = v0;
          *(float4*)(sp + 4) = v1;
        }
      }
      __syncthreads();                 // hstF safe before reuse
    }
    grid.sync();
  }
}

extern "C" void kernel_launch(void* const* d_in, const int* in_sizes, int n_in,
                              void* d_out, int out_size, void* d_ws, size_t ws_size,
                              hipStream_t stream) {
  const float* x = (const float*)d_in[0];
  const float* U0 = (const float*)d_in[1];
  const float* V0 = (const float*)d_in[2];
  const float* b0 = (const float*)d_in[3];
  const float* U = (const float*)d_in[4];
  const float* V = (const float*)d_in[5];
  const float* bL = (const float*)d_in[6];
  float* out = (float*)d_out;

  char* ws = (char*)d_ws;
  unsigned short* Wp = (unsigned short*)ws;
  unsigned short* xb = (unsigned short*)(ws + WP_BYTES);
  unsigned short* hbf = (unsigned short*)(ws + WP_BYTES + XB_BYTES);

  hipLaunchKernelGGL(k_pack_w, dim3(NTASK), dim3(256), 0, stream, U0, V0, U, V, Wp);
  hipLaunchKernelGGL(k_cvt_x, dim3(S_), dim3(256), 0, stream, x, xb);
  hipMemsetAsync(hbf, 0, HBF_ELEMS * 2, stream);

  int maxB = 0;
  hipOccupancyMaxActiveBlocksPerMultiprocessor(&maxB, k_lstm, 256, 0);
  int nwg = maxB * 256;
  if (nwg > NTASK) nwg = NTASK;
  if (nwg < 64) nwg = 64;
  int multi = (nwg < NTASK) ? 1 : 0;

  void* args[] = { (void*)&xb, (void*)&Wp, (void*)&b0, (void*)&bL,
                   (void*)&hbf, (void*)&out, (void*)&multi };
  hipError_t e = hipLaunchCooperativeKernel((void*)k_lstm, dim3(nwg), dim3(256),
                                            args, 0, stream);
  if (e != hipSuccess) {
    (void)hipGetLastError();
    nwg = 256; multi = 1;
    void* args2[] = { (void*)&xb, (void*)&Wp, (void*)&b0, (void*)&bL,
                      (void*)&hbf, (void*)&out, (void*)&multi };
    hipLaunchCooperativeKernel((void*)k_lstm, dim3(nwg), dim3(256),
                               args2, 0, stream);
  }
}